// Round 1
// baseline (138.199 us; speedup 1.0000x reference)
//
#include <hip/hip_runtime.h>

#define B 8
#define CCH 3
#define HH 512
#define WW 512
#define HW (HH * WW)
#define WIN 21
#define PAD 10
#define TSX 32
#define TSY 32
#define ROWS 52                // TSY + 2*PAD rows of horizontal sums
#define HSH 53                 // hs rows per column (53 float2 = 106 dwords stride -> balanced banks)

__global__ __launch_bounds__(256, 3) void nlm_fused_kernel(const float* __restrict__ noisy,
                                                           float* __restrict__ out) {
    // Only LDS use: double-buffered transposed horizontal sums. 2*32*53*8 = 27136 B.
    __shared__ float2 hs[2][TSX][HSH];

    const int tid = threadIdx.x;
    const int x0 = blockIdx.x * TSX;
    const int y0 = blockIdx.y * TSY;
    const int ch = blockIdx.z;

    // ---- horizontal-phase constants (tid < 208: row 0..51, segment 0..3) ----
    const int hr   = tid >> 2;
    const int hsg  = tid & 3;
    const bool hact = (tid < ROWS * 4);
    int gy = y0 + hr - PAD;
    gy = (gy < 0) ? -gy : ((gy >= HH) ? (2 * (HH - 1) - gy) : gy);
    const int hrow = gy * WW;
    const int xb   = x0 + (hsg << 3) - 12;          // 16B-aligned base; window elems are w[2..29]
    const bool hedge = (xb < 0) || (xb + 31 > WW - 1);

    // ---- vertical-phase constants (all 256: col tx, 4-row strip ty0) ----
    const int tx  = tid & 31;
    const int ty0 = (tid >> 5) << 2;
    int aoff[4], poff[4];
    int pc = x0 + tx - PAD;
    pc = (pc < 0) ? -pc : pc;                        // upper side never reflects (max 501)
    #pragma unroll
    for (int i = 0; i < 4; ++i) {
        const int ay = y0 + ty0 + i;                 // interior always
        aoff[i] = ay * WW + (x0 + tx);
        int py = ay - PAD;
        py = (py < 0) ? -py : py;                    // upper side never reflects
        poff[i] = py * WW + pc;
    }

    float num[4] = {0.f, 0.f, 0.f, 0.f};
    float den[4] = {0.f, 0.f, 0.f, 0.f};
    const float kE = (-100.0f / 441.0f) * 1.44269504088896f;  // fold 1/h^2/n/ln2

    int cur = 0;
    for (int b = 0; b < B; ++b) {
        const float* src = noisy + (size_t)(b * CCH + ch) * HW;

        // prefetch this batch's a/p operands; latency hides under horizontal phase
        float a[4], p[4];
        #pragma unroll
        for (int i = 0; i < 4; ++i) { a[i] = src[aoff[i]]; p[i] = src[poff[i]]; }

        // ---- horizontal box sums straight from global (L1/L2-resident halo) ----
        if (hact) {
            float w[32];
            if (!hedge) {
                #pragma unroll
                for (int q = 0; q < 8; ++q)
                    *(float4*)&w[q * 4] = *(const float4*)(src + hrow + xb + (q << 2));
            } else {
                #pragma unroll
                for (int m = 0; m < 28; ++m) {
                    int gx = xb + 2 + m;
                    gx = (gx < 0) ? -gx : ((gx >= WW) ? (2 * (WW - 1) - gx) : gx);
                    w[m + 2] = src[hrow + gx];
                }
            }
            float s1 = 0.f, s2 = 0.f;
            #pragma unroll
            for (int k = 0; k < 21; ++k) { s1 += w[k + 2]; s2 = fmaf(w[k + 2], w[k + 2], s2); }
            const int c0 = hsg << 3;
            hs[cur][c0][hr] = make_float2(s1, s2);
            #pragma unroll
            for (int j = 1; j < 8; ++j) {
                float vo = w[j + 1], vn = w[j + 22];
                s1 += vn - vo;
                s2 += vn * vn - vo * vo;
                hs[cur][c0 + j][hr] = make_float2(s1, s2);
            }
        }
        __syncthreads();   // the ONLY barrier per batch (double-buffered hs)

        // ---- vertical sliding sums + weights ----
        const float2* col = &hs[cur][tx][0];
        float2 h0 = col[ty0], h1 = col[ty0 + 1], h2 = col[ty0 + 2];
        float vs1 = h0.x + h1.x + h2.x;
        float vs2 = h0.y + h1.y + h2.y;
        #pragma unroll
        for (int k = 3; k <= 20; ++k) {
            float2 h = col[ty0 + k];
            vs1 += h.x;
            vs2 += h.y;
        }
        {
            float dd = fmaf(a[0], fmaf(441.f, a[0], -2.f * vs1), vs2);
            float wgt = exp2f(dd * kE);
            num[0] = fmaf(wgt, p[0], num[0]); den[0] += wgt;
        }
        #pragma unroll
        for (int i = 1; i < 4; ++i) {
            float2 hn = col[ty0 + 20 + i];
            float2 ho = (i == 1) ? h0 : ((i == 2) ? h1 : h2);
            vs1 += hn.x - ho.x;
            vs2 += hn.y - ho.y;
            float dd = fmaf(a[i], fmaf(441.f, a[i], -2.f * vs1), vs2);
            float wgt = exp2f(dd * kE);
            num[i] = fmaf(wgt, p[i], num[i]); den[i] += wgt;
        }
        cur ^= 1;
        // no trailing barrier needed: next hor writes the other hs buffer,
        // and the next __syncthreads orders vert(b) reads vs hor(b+2) writes
    }

    // ---- epilogue: identical value for all 8 batch slices ----
    #pragma unroll
    for (int i = 0; i < 4; ++i) {
        const int y = y0 + ty0 + i;
        const int x = x0 + tx;
        float v = num[i] / (den[i] + 1e-10f);
        v = v < 0.f ? 0.f : (v > 1.f ? 1.f : v);
        #pragma unroll
        for (int bb = 0; bb < B; ++bb)
            out[((size_t)(bb * CCH + ch) * HH + y) * WW + x] = v;
    }
}

extern "C" void kernel_launch(void* const* d_in, const int* in_sizes, int n_in,
                              void* d_out, int out_size, void* d_ws, size_t ws_size,
                              hipStream_t stream) {
    const float* noisy = (const float*)d_in[0];
    float* out = (float*)d_out;
    dim3 grid(WW / TSX, HH / TSY, CCH);
    nlm_fused_kernel<<<grid, dim3(256), 0, stream>>>(noisy, out);
}

// Round 2
// 99.404 us; speedup vs baseline: 1.3903x; 1.3903x over previous
//
#include <hip/hip_runtime.h>

#define B 8
#define CCH 3
#define HH 512
#define WW 512
#define WIN 21
#define PAD 10
#define TSX 32
#define TSY 16
#define PTY 36                 // TSY + 2*PAD rows staged
#define TROW 60                // tile row stride (dwords): 28r+4c sweeps all 32 banks
#define HSH 37                 // hs rows per column (odd stride -> bounded conflicts)
#define NSLOT 468              // 36 rows x 13 float4 groups
#define NTHR 128
#define HTASK (PTY * 4)        // 144 horizontal tasks

__global__ __launch_bounds__(NTHR, 3) void nlm_fused_kernel(const float* __restrict__ noisy,
                                                            float* __restrict__ out) {
    __shared__ float  tile[2][PTY][TROW];  // 17280 B, double-buffered
    __shared__ float2 hs_t[TSX][HSH];      // 9472 B  -> total 26752 B => 6 blocks/CU

    const int tid = threadIdx.x;
    const int x0 = blockIdx.x * TSX;
    const int y0 = blockIdx.y * TSY;
    const int ch = blockIdx.z;

    // ---- precompute staging slots (addresses batch-invariant) ----
    int   rowbase[4], gxs[4];
    float* ldsp[4];
    bool  valid[4], edge[4];
    #pragma unroll
    for (int k = 0; k < 4; ++k) {
        int s = tid + NTHR * k;
        valid[k] = (s < NSLOT);
        int ss = valid[k] ? s : 0;
        int r  = ss / 13;
        int c4 = ss - r * 13;
        int gy = y0 + r - PAD;
        gy = (gy < 0) ? -gy : ((gy >= HH) ? (2 * (HH - 1) - gy) : gy);
        int gx = x0 + (c4 << 2) - PAD;
        rowbase[k] = gy * WW;
        gxs[k]     = gx;
        edge[k]    = (gx < 0) || (gx > WW - 4);
        ldsp[k]    = &tile[0][r][c4 << 2];
    }

    const float* src0 = noisy + (size_t)ch * (HH * WW);
    float4 pre[4];
    // prefetch batch 0
    #pragma unroll
    for (int k = 0; k < 4; ++k) {
        if (valid[k]) {
            if (!edge[k]) {
                pre[k] = *(const float4*)(src0 + rowbase[k] + gxs[k]);
            } else {
                float tmp[4];
                #pragma unroll
                for (int t = 0; t < 4; ++t) {
                    int gx = gxs[k] + t;
                    gx = (gx < 0) ? -gx : ((gx >= WW) ? (2 * (WW - 1) - gx) : gx);
                    tmp[t] = src0[rowbase[k] + gx];
                }
                pre[k] = make_float4(tmp[0], tmp[1], tmp[2], tmp[3]);
            }
        }
    }

    float num[4] = {0.f, 0.f, 0.f, 0.f};
    float den[4] = {0.f, 0.f, 0.f, 0.f};

    const int tx  = tid & 31;
    const int ty0 = (tid >> 5) << 2;       // 4 consecutive output rows / thread
    const float kE = (-100.0f / 441.0f) * 1.44269504088896f;  // fold 1/h^2/n/ln2

    int par = 0;
    for (int b = 0; b < B; ++b) {
        // ---- stage into tile[par] (other buffer than the one read last iter) ----
        #pragma unroll
        for (int k = 0; k < 4; ++k)
            if (valid[k]) *(float4*)(ldsp[k] + par * (PTY * TROW)) = pre[k];
        __syncthreads();                   // B1: tile[par] visible; also orders V(b-1) hs reads before H(b) hs writes

        // issue next batch's global loads now; latency hides behind H+V compute
        if (b < B - 1) {
            const float* srcn = noisy + (size_t)((b + 1) * CCH + ch) * (HH * WW);
            #pragma unroll
            for (int k = 0; k < 4; ++k) {
                if (valid[k]) {
                    if (!edge[k]) {
                        pre[k] = *(const float4*)(srcn + rowbase[k] + gxs[k]);
                    } else {
                        float tmp[4];
                        #pragma unroll
                        for (int t = 0; t < 4; ++t) {
                            int gx = gxs[k] + t;
                            gx = (gx < 0) ? -gx : ((gx >= WW) ? (2 * (WW - 1) - gx) : gx);
                            tmp[t] = srcn[rowbase[k] + gx];
                        }
                        pre[k] = make_float4(tmp[0], tmp[1], tmp[2], tmp[3]);
                    }
                }
            }
        }

        // ---- horizontal box sums: 36 rows x 4 segments of 8 output cols ----
        auto hwork = [&](int t) {
            int r   = t >> 2;
            int cx0 = (t & 3) << 3;        // 0,8,16,24
            float v[28];
            #pragma unroll
            for (int q = 0; q < 7; ++q)
                *(float4*)&v[q * 4] = *(const float4*)&tile[par][r][cx0 + (q << 2)];
            float s1 = 0.f, s2 = 0.f;
            #pragma unroll
            for (int k = 0; k <= 20; ++k) { s1 += v[k]; s2 = fmaf(v[k], v[k], s2); }
            hs_t[cx0][r] = make_float2(s1, s2);
            #pragma unroll
            for (int j = 1; j < 8; ++j) {
                float vo = v[j - 1], vn = v[j + 20];
                s1 += vn - vo;
                s2 += vn * vn - vo * vo;
                hs_t[cx0 + j][r] = make_float2(s1, s2);
            }
        };
        hwork(tid);
        if (tid < HTASK - NTHR) hwork(tid + NTHR);
        __syncthreads();                   // B2: hs visible

        // ---- vertical sliding sums: 4 output rows per thread ----
        float2 h0 = hs_t[tx][ty0];
        float2 h1 = hs_t[tx][ty0 + 1];
        float2 h2 = hs_t[tx][ty0 + 2];
        float vs1 = h0.x + h1.x + h2.x;
        float vs2 = h0.y + h1.y + h2.y;
        #pragma unroll
        for (int k = 3; k <= 20; ++k) {
            float2 h = hs_t[tx][ty0 + k];
            vs1 += h.x;
            vs2 += h.y;
        }
        {
            float a = tile[par][ty0 + PAD][tx + PAD];
            float p = tile[par][ty0][tx];
            float dd = fmaf(a, fmaf(441.f, a, -2.f * vs1), vs2);
            float w = exp2f(dd * kE);
            num[0] += w * p; den[0] += w;
        }
        #pragma unroll
        for (int i = 1; i < 4; ++i) {
            float2 hn = hs_t[tx][ty0 + 20 + i];
            float2 ho = (i == 1) ? h0 : ((i == 2) ? h1 : h2);
            vs1 += hn.x - ho.x;
            vs2 += hn.y - ho.y;
            float a = tile[par][ty0 + i + PAD][tx + PAD];
            float p = tile[par][ty0 + i][tx];
            float dd = fmaf(a, fmaf(441.f, a, -2.f * vs1), vs2);
            float w = exp2f(dd * kE);
            num[i] += w * p; den[i] += w;
        }
        par ^= 1;
        // no trailing barrier: next iter stages into the OTHER tile buffer, and
        // next B1 orders this V's hs reads before the next H's hs writes
    }

    // ---- epilogue: identical value for all 8 batch slices ----
    #pragma unroll
    for (int i = 0; i < 4; ++i) {
        int y = y0 + ty0 + i;
        int x = x0 + tx;
        float v = num[i] / (den[i] + 1e-10f);
        v = v < 0.f ? 0.f : (v > 1.f ? 1.f : v);
        #pragma unroll
        for (int bb = 0; bb < B; ++bb)
            out[((size_t)(bb * CCH + ch) * HH + y) * WW + x] = v;
    }
}

extern "C" void kernel_launch(void* const* d_in, const int* in_sizes, int n_in,
                              void* d_out, int out_size, void* d_ws, size_t ws_size,
                              hipStream_t stream) {
    const float* noisy = (const float*)d_in[0];
    float* out = (float*)d_out;
    dim3 grid(WW / TSX, HH / TSY, CCH);
    nlm_fused_kernel<<<grid, dim3(NTHR), 0, stream>>>(noisy, out);
}

// Round 3
// 89.090 us; speedup vs baseline: 1.5512x; 1.1158x over previous
//
#include <hip/hip_runtime.h>

#define B 8
#define CCH 3
#define HH 512
#define WW 512
#define WIN 21
#define PAD 10
#define TSX 32
#define TSY 32
#define PTY 52                 // TSY + 2*PAD rows staged
#define TROW 60                // tile row stride (dwords): 28r+4c sweeps all 32 banks
#define HSH 53                 // hs rows per column
#define NSLOT 676              // 52 rows x 13 float4 groups

// lgkm-only barrier: LDS producer/consumer ordering WITHOUT draining vmcnt,
// so cross-batch global prefetches stay in flight across barriers (AITER pattern).
__device__ __forceinline__ void lds_barrier() {
    asm volatile("s_waitcnt lgkmcnt(0)" ::: "memory");
    __builtin_amdgcn_s_barrier();
    asm volatile("" ::: "memory");
}

__global__ __launch_bounds__(256, 3) void nlm_fused_kernel(const float* __restrict__ noisy,
                                                           float* __restrict__ out) {
    __shared__ float  tile[2][PTY][TROW];     // 24960 B (double-buffered)
    __shared__ float2 hs_t[2][TSX][HSH];      // 27136 B (double-buffered)  -> 52096 B: 3 blocks/CU

    const int tid = threadIdx.x;
    const int x0 = blockIdx.x * TSX;
    const int y0 = blockIdx.y * TSY;
    const int ch = blockIdx.z;

    // ---- precompute staging slots (addresses batch-invariant) ----
    int   rowbase[3], gxs[3];
    float* ldsp[3];
    bool  valid[3], edge[3];
    #pragma unroll
    for (int k = 0; k < 3; ++k) {
        int s = tid + 256 * k;
        valid[k] = (s < NSLOT);
        int ss = valid[k] ? s : 0;
        int r  = ss / 13;
        int c4 = ss - r * 13;
        int gy = y0 + r - PAD;
        gy = (gy < 0) ? -gy : ((gy >= HH) ? (2 * (HH - 1) - gy) : gy);
        int gx = x0 + (c4 << 2) - PAD;
        rowbase[k] = gy * WW;
        gxs[k]     = gx;
        edge[k]    = (gx < 0) || (gx > WW - 4);
        ldsp[k]    = &tile[0][r][c4 << 2];
    }

    const float* src0 = noisy + (size_t)ch * (HH * WW);
    float4 pre[3];
    // prefetch batch 0
    #pragma unroll
    for (int k = 0; k < 3; ++k) {
        if (valid[k]) {
            if (!edge[k]) {
                pre[k] = *(const float4*)(src0 + rowbase[k] + gxs[k]);
            } else {
                float tmp[4];
                #pragma unroll
                for (int t = 0; t < 4; ++t) {
                    int gx = gxs[k] + t;
                    gx = (gx < 0) ? -gx : ((gx >= WW) ? (2 * (WW - 1) - gx) : gx);
                    tmp[t] = src0[rowbase[k] + gx];
                }
                pre[k] = make_float4(tmp[0], tmp[1], tmp[2], tmp[3]);
            }
        }
    }

    float num[4] = {0.f, 0.f, 0.f, 0.f};
    float den[4] = {0.f, 0.f, 0.f, 0.f};

    const int tx  = tid & 31;
    const int ty0 = (tid >> 5) << 2;       // 4 consecutive output rows / thread
    const float kE = (-100.0f / 441.0f) * 1.44269504088896f;  // fold 1/h^2/n/ln2

    int par = 0;
    for (int b = 0; b < B; ++b) {
        // ---- stage into tile[par]; previous iter's readers used tile[par^1] ----
        #pragma unroll
        for (int k = 0; k < 3; ++k)
            if (valid[k]) *(float4*)(ldsp[k] + par * (PTY * TROW)) = pre[k];
        lds_barrier();                     // B1: tile[par] visible

        // issue next batch's global loads now; with lgkm-only barriers these
        // stay in flight through B2 and are waited only at next iter's ds_write
        if (b < B - 1) {
            const float* srcn = noisy + (size_t)((b + 1) * CCH + ch) * (HH * WW);
            #pragma unroll
            for (int k = 0; k < 3; ++k) {
                if (valid[k]) {
                    if (!edge[k]) {
                        pre[k] = *(const float4*)(srcn + rowbase[k] + gxs[k]);
                    } else {
                        float tmp[4];
                        #pragma unroll
                        for (int t = 0; t < 4; ++t) {
                            int gx = gxs[k] + t;
                            gx = (gx < 0) ? -gx : ((gx >= WW) ? (2 * (WW - 1) - gx) : gx);
                            tmp[t] = srcn[rowbase[k] + gx];
                        }
                        pre[k] = make_float4(tmp[0], tmp[1], tmp[2], tmp[3]);
                    }
                }
            }
        }

        // ---- horizontal box sums: 52 rows x 4 segments of 8 output cols ----
        if (tid < PTY * 4) {
            int r   = tid >> 2;
            int cx0 = (tid & 3) << 3;      // 0,8,16,24
            float v[28];
            #pragma unroll
            for (int q = 0; q < 7; ++q)
                *(float4*)&v[q * 4] = *(const float4*)&tile[par][r][cx0 + (q << 2)];
            float s1 = 0.f, s2 = 0.f;
            #pragma unroll
            for (int k = 0; k <= 20; ++k) { s1 += v[k]; s2 = fmaf(v[k], v[k], s2); }
            hs_t[par][cx0][r] = make_float2(s1, s2);
            #pragma unroll
            for (int j = 1; j < 8; ++j) {
                float vo = v[j - 1], vn = v[j + 20];
                s1 += vn - vo;
                s2 += vn * vn - vo * vo;
                hs_t[par][cx0 + j][r] = make_float2(s1, s2);
            }
        }
        lds_barrier();                     // B2: hs_t[par] visible

        // ---- vertical sliding sums: 4 output rows per thread ----
        float2 h0 = hs_t[par][tx][ty0];
        float2 h1 = hs_t[par][tx][ty0 + 1];
        float2 h2 = hs_t[par][tx][ty0 + 2];
        float vs1 = h0.x + h1.x + h2.x;
        float vs2 = h0.y + h1.y + h2.y;
        #pragma unroll
        for (int k = 3; k <= 20; ++k) {
            float2 h = hs_t[par][tx][ty0 + k];
            vs1 += h.x;
            vs2 += h.y;
        }
        {
            float a = tile[par][ty0 + PAD][tx + PAD];
            float p = tile[par][ty0][tx];
            float dd = fmaf(a, fmaf(441.f, a, -2.f * vs1), vs2);
            float w = exp2f(dd * kE);
            num[0] += w * p; den[0] += w;
        }
        #pragma unroll
        for (int i = 1; i < 4; ++i) {
            float2 hn = hs_t[par][tx][ty0 + 20 + i];
            float2 ho = (i == 1) ? h0 : ((i == 2) ? h1 : h2);
            vs1 += hn.x - ho.x;
            vs2 += hn.y - ho.y;
            float a = tile[par][ty0 + i + PAD][tx + PAD];
            float p = tile[par][ty0 + i][tx];
            float dd = fmaf(a, fmaf(441.f, a, -2.f * vs1), vs2);
            float w = exp2f(dd * kE);
            num[i] += w * p; den[i] += w;
        }
        par ^= 1;
        // no loop-top barrier: next stage writes the OTHER tile buffer, and the
        // intervening lgkm-draining barriers order this V's reads before any
        // same-buffer overwrite two iterations out
    }

    // ---- epilogue: identical value for all 8 batch slices ----
    #pragma unroll
    for (int i = 0; i < 4; ++i) {
        int y = y0 + ty0 + i;
        int x = x0 + tx;
        float v = num[i] / (den[i] + 1e-10f);
        v = v < 0.f ? 0.f : (v > 1.f ? 1.f : v);
        #pragma unroll
        for (int b = 0; b < B; ++b)
            out[((size_t)(b * CCH + ch) * HH + y) * WW + x] = v;
    }
}

extern "C" void kernel_launch(void* const* d_in, const int* in_sizes, int n_in,
                              void* d_out, int out_size, void* d_ws, size_t ws_size,
                              hipStream_t stream) {
    const float* noisy = (const float*)d_in[0];
    float* out = (float*)d_out;
    dim3 grid(WW / TSX, HH / TSY, CCH);
    nlm_fused_kernel<<<grid, dim3(256), 0, stream>>>(noisy, out);
}